// Round 1
// 1218.710 us; speedup vs baseline: 1.1610x; 1.1610x over previous
//
#include <hip/hip_runtime.h>
#include <hip/hip_bf16.h>
#include <math.h>

#define NB 4
#define SQ 1024
#define DM 1024
#define NH 16
#define HDm 64
#define NE 8
#define FFd 4096
#define NTOK 4096
#define RTOT 9216
#define EPSF 1e-6f

typedef __attribute__((ext_vector_type(8))) short bf16x8_t;
typedef __attribute__((ext_vector_type(4))) float f32x4_t;
typedef const __attribute__((address_space(1))) void* gas_t;
typedef __attribute__((address_space(3))) void* las_t;

__device__ __forceinline__ float b2f(unsigned short u){
  return __uint_as_float(((unsigned int)u) << 16);
}
__device__ __forceinline__ unsigned short f2b(float f){
  __hip_bfloat16 h = __float2bfloat16(f);
  unsigned short u;
  __builtin_memcpy(&u, &h, 2);
  return u;
}

// ---------------- fp32 -> bf16 convert ----------------
__global__ __launch_bounds__(256) void convert_k(const float* __restrict__ s,
                                                 unsigned short* __restrict__ d, int n4){
  int i = blockIdx.x*256 + threadIdx.x;
  if (i >= n4) return;
  float4 v = ((const float4*)s)[i];
  ushort4 o; o.x=f2b(v.x); o.y=f2b(v.y); o.z=f2b(v.z); o.w=f2b(v.w);
  ((ushort4*)d)[i] = o;
}

// ---------------- fp32 -> bf16 hi/lo split ----------------
__global__ __launch_bounds__(256) void split_k(const float* __restrict__ s,
                                               unsigned short* __restrict__ hi,
                                               unsigned short* __restrict__ lo, int n4){
  int i = blockIdx.x*256 + threadIdx.x;
  if (i >= n4) return;
  float4 v = ((const float4*)s)[i];
  ushort4 h, l;
  h.x=f2b(v.x); l.x=f2b(v.x - b2f(h.x));
  h.y=f2b(v.y); l.y=f2b(v.y - b2f(h.y));
  h.z=f2b(v.z); l.z=f2b(v.z - b2f(h.z));
  h.w=f2b(v.w); l.w=f2b(v.w - b2f(h.w));
  ((ushort4*)hi)[i] = h;
  ((ushort4*)lo)[i] = l;
}

// ---------------- RMSNorm (fp32 out), one block per row ----------------
__global__ __launch_bounds__(256) void rmsnorm_k(const float* __restrict__ x,
                                                 const float* __restrict__ w,
                                                 float* __restrict__ o){
  int row = blockIdx.x; int t = threadIdx.x;
  float4 v = ((const float4*)(x + (size_t)row*DM))[t];
  float ss = v.x*v.x + v.y*v.y + v.z*v.z + v.w*v.w;
  #pragma unroll
  for (int d=32; d; d>>=1) ss += __shfl_down(ss, d, 64);
  __shared__ float red[4];
  int wid = t>>6, ln = t&63;
  if (ln==0) red[wid] = ss;
  __syncthreads();
  float tot = red[0]+red[1]+red[2]+red[3];
  float sc = 1.0f/sqrtf(tot*(1.0f/DM) + EPSF);
  float4 wv = ((const float4*)w)[t];
  float4 ov = { v.x*sc*wv.x, v.y*sc*wv.y, v.z*sc*wv.z, v.w*sc*wv.w };
  ((float4*)(o + (size_t)row*DM))[t] = ov;
}

// ---------------- RMSNorm with split bf16 output ----------------
__global__ __launch_bounds__(256) void rmsnorm_split_k(const float* __restrict__ x,
                                                       const float* __restrict__ w,
                                                       unsigned short* __restrict__ hi,
                                                       unsigned short* __restrict__ lo){
  int row = blockIdx.x; int t = threadIdx.x;
  float4 v = ((const float4*)(x + (size_t)row*DM))[t];
  float ss = v.x*v.x + v.y*v.y + v.z*v.z + v.w*v.w;
  #pragma unroll
  for (int d=32; d; d>>=1) ss += __shfl_down(ss, d, 64);
  __shared__ float red[4];
  int wid = t>>6, ln = t&63;
  if (ln==0) red[wid] = ss;
  __syncthreads();
  float tot = red[0]+red[1]+red[2]+red[3];
  float sc = 1.0f/sqrtf(tot*(1.0f/DM) + EPSF);
  float4 wv = ((const float4*)w)[t];
  float4 ov = { v.x*sc*wv.x, v.y*sc*wv.y, v.z*sc*wv.z, v.w*sc*wv.w };
  ushort4 h, l;
  h.x=f2b(ov.x); l.x=f2b(ov.x - b2f(h.x));
  h.y=f2b(ov.y); l.y=f2b(ov.y - b2f(h.y));
  h.z=f2b(ov.z); l.z=f2b(ov.z - b2f(h.z));
  h.w=f2b(ov.w); l.w=f2b(ov.w - b2f(h.w));
  ((ushort4*)(hi + (size_t)row*DM))[t] = h;
  ((ushort4*)(lo + (size_t)row*DM))[t] = l;
}

// ---------------- split-bf16 MFMA NT GEMM: C = (Ah+Al)@(Bh+Bl)^T (+resid) ------
__global__ __launch_bounds__(256) void gemm_nt_split(
  const unsigned short* __restrict__ Ah, const unsigned short* __restrict__ Al,
  const unsigned short* __restrict__ Bh0, const unsigned short* __restrict__ Bl0,
  const unsigned short* __restrict__ Bh1, const unsigned short* __restrict__ Bl1,
  const unsigned short* __restrict__ Bh2, const unsigned short* __restrict__ Bl2,
  float* __restrict__ C0, float* __restrict__ C1, float* __restrict__ C2,
  const float* __restrict__ resid, int Kd, int Ncols)
{
  const unsigned short* Bh = (blockIdx.z==0)?Bh0:(blockIdx.z==1)?Bh1:Bh2;
  const unsigned short* Bl = (blockIdx.z==0)?Bl0:(blockIdx.z==1)?Bl1:Bl2;
  float* C = (blockIdx.z==0)?C0:(blockIdx.z==1)?C1:C2;
  __shared__ unsigned short AsH[128*32];
  __shared__ unsigned short AsL[128*32];
  __shared__ unsigned short BsH[128*32];
  __shared__ unsigned short BsL[128*32];
  const int t = threadIdx.x;
  const int w = t>>6, lane = t&63;
  const int wm = w>>1, wn = w&1;
  const int lm = lane&15, fk = (lane>>4)*8;
  const int row0 = blockIdx.y*128, col0 = blockIdx.x*128;
  f32x4_t acc[4][4];
  #pragma unroll
  for (int i=0;i<4;i++)
    #pragma unroll
    for (int j=0;j<4;j++){ f32x4_t z = {0.f,0.f,0.f,0.f}; acc[i][j]=z; }
  for (int k0=0;k0<Kd;k0+=32){
    __syncthreads();
    #pragma unroll
    for (int j=0;j<2;j++){
      const int chunk = j*4 + w;
      const int gt = chunk*64 + lane;
      const int rw_ = gt>>2, kp = (gt&3)*8;
      const size_t aoff = (size_t)(row0+rw_)*Kd + k0 + kp;
      const size_t boff = (size_t)(col0+rw_)*Kd + k0 + kp;
      __builtin_amdgcn_global_load_lds((gas_t)(Ah + aoff), (las_t)(AsH + chunk*512), 16, 0, 0);
      __builtin_amdgcn_global_load_lds((gas_t)(Al + aoff), (las_t)(AsL + chunk*512), 16, 0, 0);
      __builtin_amdgcn_global_load_lds((gas_t)(Bh + boff), (las_t)(BsH + chunk*512), 16, 0, 0);
      __builtin_amdgcn_global_load_lds((gas_t)(Bl + boff), (las_t)(BsL + chunk*512), 16, 0, 0);
    }
    __syncthreads();
    bf16x8_t ah[4], al[4], bh[4], bl[4];
    #pragma unroll
    for (int f=0;f<4;f++){
      const size_t ao = (size_t)(wm*64 + f*16 + lm)*32 + fk;
      const size_t bo = (size_t)(wn*64 + f*16 + lm)*32 + fk;
      ah[f] = *(const bf16x8_t*)(AsH + ao);
      al[f] = *(const bf16x8_t*)(AsL + ao);
      bh[f] = *(const bf16x8_t*)(BsH + bo);
      bl[f] = *(const bf16x8_t*)(BsL + bo);
    }
    #pragma unroll
    for (int i=0;i<4;i++)
      #pragma unroll
      for (int j=0;j<4;j++){
        acc[i][j] = __builtin_amdgcn_mfma_f32_16x16x32_bf16(ah[i], bh[j], acc[i][j], 0, 0, 0);
        acc[i][j] = __builtin_amdgcn_mfma_f32_16x16x32_bf16(al[i], bh[j], acc[i][j], 0, 0, 0);
        acc[i][j] = __builtin_amdgcn_mfma_f32_16x16x32_bf16(ah[i], bl[j], acc[i][j], 0, 0, 0);
      }
  }
  const int rbase = row0 + wm*64 + (lane>>4)*4;
  const int cbase = col0 + wn*64 + lm;
  #pragma unroll
  for (int i=0;i<4;i++)
    #pragma unroll
    for (int j=0;j<4;j++)
      #pragma unroll
      for (int r=0;r<4;r++){
        const size_t idx = (size_t)(rbase + i*16 + r)*Ncols + cbase + j*16;
        float v = acc[i][j][r];
        if (resid) v += resid[idx];
        C[idx] = v;
      }
}

// ---------------- RoPE -> bf16 (q scaled by 1/8 for attention) ----------------
__global__ __launch_bounds__(256) void rope_bf16_k(const float* __restrict__ qh,
  const float* __restrict__ kh, const float* __restrict__ fc, const float* __restrict__ fs,
  unsigned short* __restrict__ qb, unsigned short* __restrict__ kb){
  int idx = blockIdx.x*256 + threadIdx.x;
  if (idx >= NTOK*NH*32) return;
  int i = idx & 31;
  int h = (idx>>5) & (NH-1);
  int n = idx >> 9;
  int s = n & (SQ-1);
  float c = fc[s*32+i], sn = fs[s*32+i];
  size_t base = (size_t)n*DM + h*HDm + 2*i;
  float xr = qh[base], xi = qh[base+1];
  float or_ = (xr*c - xi*sn) * 0.125f;
  float oi  = (xr*sn + xi*c) * 0.125f;
  unsigned int pq = (unsigned int)f2b(or_) | ((unsigned int)f2b(oi) << 16);
  *(unsigned int*)(qb + base) = pq;
  xr = kh[base]; xi = kh[base+1];
  or_ = xr*c - xi*sn; oi = xr*sn + xi*c;
  unsigned int pk = (unsigned int)f2b(or_) | ((unsigned int)f2b(oi) << 16);
  *(unsigned int*)(kb + base) = pk;
}

// ---------------- V transpose+convert: vh fp32 [tok][DM] -> vT bf16 [(b,h,hd)][S] ----
__global__ __launch_bounds__(256) void vtrans_k(const float* __restrict__ vh,
                                                unsigned short* __restrict__ vT){
  __shared__ unsigned short Lt[64][72];
  const int st = blockIdx.x, bh = blockIdx.y;
  const int b = bh >> 4, h = bh & 15;
  const int t = threadIdx.x;
  const int s0 = st*64;
  const int sr = t >> 2, hq = (t & 3) * 16;
  const float* src = vh + ((size_t)(b*SQ + s0 + sr))*DM + h*HDm + hq;
  #pragma unroll
  for (int i=0;i<4;i++){
    float4 v = *(const float4*)(src + 4*i);
    Lt[hq+4*i+0][sr] = f2b(v.x);
    Lt[hq+4*i+1][sr] = f2b(v.y);
    Lt[hq+4*i+2][sr] = f2b(v.z);
    Lt[hq+4*i+3][sr] = f2b(v.w);
  }
  __syncthreads();
  const int hd = t >> 2, sq = (t & 3) * 16;
  unsigned short* dst = vT + ((size_t)bh*HDm + hd)*SQ + s0 + sq;
  #pragma unroll
  for (int i=0;i<2;i++){
    bf16x8_t x = *(const bf16x8_t*)&Lt[hd][sq + 8*i];
    *(bf16x8_t*)(dst + 8*i) = x;
  }
}

// ---------------- MFMA flash attention, 64 q-rows x 64-key tiles --------------
// block = 256 thr = 4 waves; wave w owns q-rows [w*16, w*16+16)
// writes ctx hi/lo bf16 split directly (feeds split wo-GEMM)
__global__ __launch_bounds__(256) void flash_mfma_k(
  const unsigned short* __restrict__ qb, const unsigned short* __restrict__ kb,
  const unsigned short* __restrict__ vT,
  unsigned short* __restrict__ ctxh, unsigned short* __restrict__ ctxl,
  const int* __restrict__ causp)
{
  __shared__ unsigned short Qs[2*64*32];   // [c][qrow][32]
  __shared__ unsigned short Ks[2*64*32];   // [c][key][32]
  __shared__ unsigned short Vt[2*64*32];   // [c=key/32][hd][key&31]
  __shared__ unsigned short Ps[2*64*32];   // [c=key/32][qrow][key&31], XOR-swizzled
  const int qt = blockIdx.x;
  const int bh = blockIdx.y;
  const int b = bh >> 4, h = bh & 15;
  const int t = threadIdx.x;
  const int w = t >> 6, lane = t & 63;
  const int lm = lane & 15, g = lane >> 4, fk = g * 8;
  const int q0 = qt * 64;
  const size_t qkoff = (size_t)b * SQ * DM + (size_t)h * HDm;
  const size_t voff  = ((size_t)bh * HDm) * SQ;

  // stage Q once (8 sub-chunks of 16 rows x 32 k)
  #pragma unroll
  for (int j=0;j<2;j++){
    const int s = j*4 + w;
    const int c = s >> 2, r0 = (s & 3) * 16;
    const int row = r0 + (lane >> 2), kp = (lane & 3) * 8;
    __builtin_amdgcn_global_load_lds((gas_t)(qb + qkoff + (size_t)(q0+row)*DM + c*32 + kp),
                                     (las_t)(Qs + s*512), 16, 0, 0);
  }
  __syncthreads();
  bf16x8_t aq0 = *(const bf16x8_t*)(Qs + 0*2048 + (w*16+lm)*32 + fk);
  bf16x8_t aq1 = *(const bf16x8_t*)(Qs + 1*2048 + (w*16+lm)*32 + fk);

  const int causal = *causp;
  const int ktmax = causal ? qt : (SQ/64 - 1);
  f32x4_t O[4];
  #pragma unroll
  for (int j=0;j<4;j++){ f32x4_t z={0.f,0.f,0.f,0.f}; O[j]=z; }
  float mrow[4], lrow[4];
  #pragma unroll
  for (int r=0;r<4;r++){ mrow[r] = -3e30f; lrow[r] = 0.f; }

  for (int kt=0; kt<=ktmax; ++kt){
    const int k0 = kt*64;
    __syncthreads();   // all waves done reading Ks/Vt of prev tile
    #pragma unroll
    for (int j=0;j<2;j++){
      const int s = j*4 + w;
      const int c = s >> 2, r0 = (s & 3) * 16;
      const int row = r0 + (lane >> 2), kp = (lane & 3) * 8;
      __builtin_amdgcn_global_load_lds((gas_t)(kb + qkoff + (size_t)(k0+row)*DM + c*32 + kp),
                                       (las_t)(Ks + s*512), 16, 0, 0);
      __builtin_amdgcn_global_load_lds((gas_t)(vT + voff + (size_t)row*SQ + k0 + c*32 + kp),
                                       (las_t)(Vt + s*512), 16, 0, 0);
    }
    __syncthreads();

    // ---- S = Qs @ Ks^T (pre-scaled by 1/8 via qb) ----
    f32x4_t Sv[4];
    #pragma unroll
    for (int j=0;j<4;j++){ f32x4_t z={0.f,0.f,0.f,0.f}; Sv[j]=z; }
    #pragma unroll
    for (int j=0;j<4;j++){
      bf16x8_t b0 = *(const bf16x8_t*)(Ks + 0*2048 + (j*16+lm)*32 + fk);
      bf16x8_t b1 = *(const bf16x8_t*)(Ks + 1*2048 + (j*16+lm)*32 + fk);
      Sv[j] = __builtin_amdgcn_mfma_f32_16x16x32_bf16(aq0, b0, Sv[j], 0, 0, 0);
      Sv[j] = __builtin_amdgcn_mfma_f32_16x16x32_bf16(aq1, b1, Sv[j], 0, 0, 0);
    }
    // causal mask (diagonal tile only)
    const int rowq = q0 + w*16 + g*4;
    if (causal && kt == qt){
      #pragma unroll
      for (int j=0;j<4;j++){
        const int col = k0 + j*16 + lm;
        #pragma unroll
        for (int r=0;r<4;r++)
          if (col > rowq + r) Sv[j][r] = -3e30f;
      }
    }
    // ---- online softmax: per-row max/sum via in-reg + 16-lane xor reduce ----
    float alpha[4];
    #pragma unroll
    for (int r=0;r<4;r++){
      float m_ = fmaxf(fmaxf(Sv[0][r],Sv[1][r]), fmaxf(Sv[2][r],Sv[3][r]));
      #pragma unroll
      for (int d=1; d<16; d<<=1) m_ = fmaxf(m_, __shfl_xor(m_, d, 64));
      const float mn = fmaxf(mrow[r], m_);
      alpha[r] = __expf(mrow[r] - mn);
      mrow[r] = mn;
    }
    #pragma unroll
    for (int r=0;r<4;r++){
      const int qrow = w*16 + g*4 + r;
      float rs = 0.f;
      #pragma unroll
      for (int j=0;j<4;j++){
        const float p = __expf(Sv[j][r] - mrow[r]);
        rs += p;
        const int key5 = (((j&1)<<4) | lm) ^ (g<<3);   // XOR swizzle keyed on qrow>>2
        Ps[(j>>1)*2048 + qrow*32 + key5] = f2b(p);
      }
      #pragma unroll
      for (int d=1; d<16; d<<=1) rs += __shfl_xor(rs, d, 64);
      lrow[r] = lrow[r]*alpha[r] + rs;
      #pragma unroll
      for (int j=0;j<4;j++) O[j][r] *= alpha[r];
    }
    // ---- O += P @ V  (Ps rows are wave-private: no barrier needed) ----
    const int fkp = fk ^ (((lm>>2)&3)<<3);
    bf16x8_t pa0 = *(const bf16x8_t*)(Ps + 0*2048 + (w*16+lm)*32 + fkp);
    bf16x8_t pa1 = *(const bf16x8_t*)(Ps + 1*2048 + (w*16+lm)*32 + fkp);
    #pragma unroll
    for (int j=0;j<4;j++){
      bf16x8_t v0 = *(const bf16x8_t*)(Vt + 0*2048 + (j*16+lm)*32 + fk);
      bf16x8_t v1 = *(const bf16x8_t*)(Vt + 1*2048 + (j*16+lm)*32 + fk);
      O[j] = __builtin_amdgcn_mfma_f32_16x16x32_bf16(pa0, v0, O[j], 0, 0, 0);
      O[j] = __builtin_amdgcn_mfma_f32_16x16x32_bf16(pa1, v1, O[j], 0, 0, 0);
    }
  }
  // ---- epilogue: O/l, write split bf16 ctx ----
  #pragma unroll
  for (int r=0;r<4;r++){
    const float il = 1.0f / lrow[r];
    const size_t rowtok = (size_t)(q0 + w*16 + g*4 + r);
    #pragma unroll
    for (int j=0;j<4;j++){
      const float v = O[j][r] * il;
      const unsigned short hi = f2b(v);
      const float lo = v - b2f(hi);
      const size_t idx = qkoff + rowtok*DM + j*16 + lm;
      ctxh[idx] = hi;
      ctxl[idx] = f2b(lo);
    }
  }
}

// ---------------- router: fp32 logits, top-2, counts ----------------
__global__ __launch_bounds__(256) void router_k(
  const float* __restrict__ hn, const float* __restrict__ rw, const float* __restrict__ rb,
  int* __restrict__ topi, float* __restrict__ topp, int* __restrict__ counts)
{
  const int n = blockIdx.x, t = threadIdx.x;
  float4 x = ((const float4*)(hn + (size_t)n*DM))[t];
  float p[NE];
  #pragma unroll
  for (int e=0;e<NE;e++){
    float4 wv = ((const float4*)(rw + (size_t)e*DM))[t];
    p[e] = x.x*wv.x + x.y*wv.y + x.z*wv.z + x.w*wv.w;
  }
  #pragma unroll
  for (int e=0;e<NE;e++)
    #pragma unroll
    for (int d=32; d; d>>=1) p[e] += __shfl_down(p[e], d, 64);
  __shared__ float red[4][NE];
  int wid=t>>6, ln=t&63;
  if (ln==0){
    #pragma unroll
    for (int e=0;e<NE;e++) red[wid][e]=p[e];
  }
  __syncthreads();
  if (t==0){
    float v1=-3e30f, v2=-3e30f; int i1=0, i2=0;
    for (int e=0;e<NE;e++){
      float v = red[0][e]+red[1][e]+red[2][e]+red[3][e]+rb[e];
      if (v > v1){ v2=v1;i2=i1; v1=v;i1=e; }
      else if (v > v2){ v2=v;i2=e; }
    }
    float ex = expf(v2-v1);
    float g1 = 1.0f/(1.0f+ex);
    float g2 = ex*g1;
    topi[2*n]=i1; topi[2*n+1]=i2;
    topp[2*n]=g1; topp[2*n+1]=g2;
    atomicAdd(&counts[i1],1); atomicAdd(&counts[i2],1);
  }
}

__global__ void offsets_k(const int* __restrict__ counts, int* __restrict__ offs){
  if (blockIdx.x==0 && threadIdx.x==0){
    int run=0;
    for (int e=0;e<NE;e++){ offs[e]=run; run += (counts[e]+127)&~127; }
    offs[NE]=run;
  }
}

__global__ __launch_bounds__(256) void assign_k(const int* __restrict__ topi,
  const int* __restrict__ offs, int* __restrict__ cursor,
  int* __restrict__ list, int* __restrict__ inv){
  int t = blockIdx.x*256 + threadIdx.x;
  if (t >= NTOK*2) return;
  int e = topi[t];
  int slot = atomicAdd(&cursor[e], 1);
  int pos = offs[e] + slot;
  list[pos] = t>>1;
  inv[t] = pos;
}

__global__ __launch_bounds__(256) void gather_k(const float* __restrict__ hn,
  const int* __restrict__ offs, const int* __restrict__ counts, const int* __restrict__ list,
  unsigned short* __restrict__ xg){
  const int p = blockIdx.x;
  if (p >= offs[NE]) return;
  int e=0;
  while (offs[e+1] <= p) ++e;
  const int t = threadIdx.x;
  ushort4 o;
  if (p - offs[e] < counts[e]){
    int n = list[p];
    float4 x = ((const float4*)(hn + (size_t)n*DM))[t];
    o.x=f2b(x.x); o.y=f2b(x.y); o.z=f2b(x.z); o.w=f2b(x.w);
  } else { o.x=0; o.y=0; o.z=0; o.w=0; }
  ((ushort4*)(xg + (size_t)p*DM))[t] = o;
}

// ---------------- bf16 MFMA NT GEMM over expert-compacted rows ----------------
__global__ __launch_bounds__(256) void gemm_moe_bf16(
  const unsigned short* __restrict__ Aall, const unsigned short* __restrict__ Wall,
  unsigned short* __restrict__ Call, const int* __restrict__ offs, int Kd, int Ncols)
{
  const int row0 = blockIdx.y*128;
  if (row0 >= offs[NE]) return;
  int e=0;
  while (offs[e+1] <= row0) ++e;
  const unsigned short* Wp = Wall + (size_t)e*Ncols*Kd;
  const int col0 = blockIdx.x*128;
  __shared__ unsigned short As[128*32];
  __shared__ unsigned short Bs[128*32];
  const int t = threadIdx.x;
  const int w = t>>6, lane = t&63;
  const int wm = w>>1, wn = w&1;
  const int lm = lane&15, fk = (lane>>4)*8;
  f32x4_t acc[4][4];
  #pragma unroll
  for (int i=0;i<4;i++)
    #pragma unroll
    for (int j=0;j<4;j++){ f32x4_t z = {0.f,0.f,0.f,0.f}; acc[i][j]=z; }
  for (int k0=0;k0<Kd;k0+=32){
    __syncthreads();
    #pragma unroll
    for (int j=0;j<2;j++){
      const int chunk = j*4 + w;
      const int gt = chunk*64 + lane;
      const int rw_ = gt>>2, kp = (gt&3)*8;
      __builtin_amdgcn_global_load_lds((gas_t)(Aall + (size_t)(row0+rw_)*Kd + k0 + kp),
                                       (las_t)(As + chunk*512), 16, 0, 0);
      __builtin_amdgcn_global_load_lds((gas_t)(Wp + (size_t)(col0+rw_)*Kd + k0 + kp),
                                       (las_t)(Bs + chunk*512), 16, 0, 0);
    }
    __syncthreads();
    bf16x8_t af[4], bfr[4];
    #pragma unroll
    for (int f=0;f<4;f++){
      af[f]  = *(const bf16x8_t*)(As + (size_t)(wm*64 + f*16 + lm)*32 + fk);
      bfr[f] = *(const bf16x8_t*)(Bs + (size_t)(wn*64 + f*16 + lm)*32 + fk);
    }
    #pragma unroll
    for (int i=0;i<4;i++)
      #pragma unroll
      for (int j=0;j<4;j++)
        acc[i][j] = __builtin_amdgcn_mfma_f32_16x16x32_bf16(af[i], bfr[j], acc[i][j], 0, 0, 0);
  }
  const int rbase = row0 + wm*64 + (lane>>4)*4;
  const int cbase = col0 + wn*64 + lm;
  #pragma unroll
  for (int i=0;i<4;i++)
    #pragma unroll
    for (int j=0;j<4;j++)
      #pragma unroll
      for (int r=0;r<4;r++)
        Call[(size_t)(rbase + i*16 + r)*Ncols + cbase + j*16] = f2b(acc[i][j][r]);
}

__global__ __launch_bounds__(256) void silu_mul_k(unsigned short* __restrict__ h1,
                                                  const unsigned short* __restrict__ h3){
  size_t i = (size_t)blockIdx.x*256 + threadIdx.x;
  ushort4 a = ((const ushort4*)h1)[i];
  ushort4 b = ((const ushort4*)h3)[i];
  ushort4 o;
  float fa, fb, s_;
  fa=b2f(a.x); fb=b2f(b.x); s_=fa/(1.f+__expf(-fa)); o.x=f2b(s_*fb);
  fa=b2f(a.y); fb=b2f(b.y); s_=fa/(1.f+__expf(-fa)); o.y=f2b(s_*fb);
  fa=b2f(a.z); fb=b2f(b.z); s_=fa/(1.f+__expf(-fa)); o.z=f2b(s_*fb);
  fa=b2f(a.w); fb=b2f(b.w); s_=fa/(1.f+__expf(-fa)); o.w=f2b(s_*fb);
  ((ushort4*)h1)[i] = o;
}

__global__ __launch_bounds__(256) void combine_k(const float* __restrict__ h,
  const unsigned short* __restrict__ yb, const float* __restrict__ topp,
  const int* __restrict__ inv, float* __restrict__ out)
{
  const int n = blockIdx.x, t = threadIdx.x;
  const int p0 = inv[2*n], p1 = inv[2*n+1];
  const float g0 = topp[2*n], g1 = topp[2*n+1];
  float4 hv = ((const float4*)(h + (size_t)n*DM))[t];
  ushort4 y0 = ((const ushort4*)(yb + (size_t)p0*DM))[t];
  ushort4 y1 = ((const ushort4*)(yb + (size_t)p1*DM))[t];
  float4 ov;
  ov.x = hv.x + g0*b2f(y0.x) + g1*b2f(y1.x);
  ov.y = hv.y + g0*b2f(y0.y) + g1*b2f(y1.y);
  ov.z = hv.z + g0*b2f(y0.z) + g1*b2f(y1.z);
  ov.w = hv.w + g0*b2f(y0.w) + g1*b2f(y1.w);
  ((float4*)(out + (size_t)n*DM))[t] = ov;
}

extern "C" void kernel_launch(void* const* d_in, const int* in_sizes, int n_in,
                              void* d_out, int out_size, void* d_ws, size_t ws_size,
                              hipStream_t stream)
{
  (void)in_sizes; (void)n_in; (void)out_size; (void)ws_size;
  const float* q    = (const float*)d_in[0];
  const float* fc   = (const float*)d_in[3];
  const float* fs   = (const float*)d_in[4];
  const float* attw = (const float*)d_in[5];
  const float* ffnw = (const float*)d_in[6];
  const float* wq   = (const float*)d_in[7];
  const float* wk   = (const float*)d_in[8];
  const float* wv   = (const float*)d_in[9];
  const float* wo   = (const float*)d_in[10];
  const float* rw   = (const float*)d_in[11];
  const float* rb   = (const float*)d_in[12];
  const float* w1   = (const float*)d_in[13];
  const float* w2   = (const float*)d_in[14];
  const float* w3   = (const float*)d_in[15];
  const int*   caus = (const int*)d_in[16];
  float* out = (float*)d_out;

  char* ws = (char*)d_ws;
  size_t off = 0;
  auto take = [&](size_t bytes)->char*{ char* r = ws + off; off += (bytes + 255) & ~(size_t)255; return r; };
  unsigned short* qnh = (unsigned short*)take((size_t)NTOK*DM*2);
  unsigned short* qnl = (unsigned short*)take((size_t)NTOK*DM*2);
  float* qh   = (float*)take((size_t)NTOK*DM*4);
  float* kh   = (float*)take((size_t)NTOK*DM*4);
  float* vh   = (float*)take((size_t)NTOK*DM*4);
  float* hbuf = (float*)take((size_t)NTOK*DM*4);
  unsigned short* h1  = (unsigned short*)take((size_t)RTOT*FFd*2);
  unsigned short* h3  = (unsigned short*)take((size_t)RTOT*FFd*2);
  unsigned short* yb  = (unsigned short*)take((size_t)RTOT*DM*2);
  unsigned short* w1b = (unsigned short*)take((size_t)NE*FFd*DM*2);
  unsigned short* w3b = (unsigned short*)take((size_t)NE*FFd*DM*2);
  unsigned short* w2b = (unsigned short*)take((size_t)NE*FFd*DM*2);
  int*   counts = (int*)take(64);
  int*   cursor = counts + 8;
  int*   offs   = (int*)take(64);
  int*   topi   = (int*)take((size_t)NTOK*2*4);
  float* topp   = (float*)take((size_t)NTOK*2*4);
  int*   list   = (int*)take((size_t)RTOT*4);
  int*   inv    = (int*)take((size_t)NTOK*2*4);

  // aliases (lifetimes disjoint):
  unsigned short* ctxh = qnh;                     // flash ctx hi/lo overwrite qn splits
  unsigned short* ctxl = qnl;
  float* hn = kh;                                 // rmsnorm2 output overwrites kh (dead post-rope)
  unsigned short* xg = yb;                        // gathered tokens; dead before yb written
  unsigned short* wqh = (unsigned short*)h1;      // attn weight splits live in h1 region (dead before MoE)
  unsigned short* wql = wqh + (size_t)DM*DM;
  unsigned short* wkh = wql + (size_t)DM*DM;
  unsigned short* wkl = wkh + (size_t)DM*DM;
  unsigned short* wvh = wkl + (size_t)DM*DM;
  unsigned short* wvl = wvh + (size_t)DM*DM;
  unsigned short* woh = wvl + (size_t)DM*DM;
  unsigned short* wol = woh + (size_t)DM*DM;
  unsigned short* qb  = wqh + 8*(size_t)DM*DM;    // bf16 roped Q (dead before MoE writes h1)
  unsigned short* kb  = qb + (size_t)NTOK*DM;     // bf16 roped K
  unsigned short* vTb = (unsigned short*)h3;      // bf16 V^T (dead before h3 written)

  const int nw4 = NE*FFd*DM/4;  // 8388608
  convert_k<<<nw4/256, 256, 0, stream>>>(w1, w1b, nw4);
  convert_k<<<nw4/256, 256, 0, stream>>>(w3, w3b, nw4);
  convert_k<<<nw4/256, 256, 0, stream>>>(w2, w2b, nw4);

  const int nwq4 = DM*DM/4;  // 262144
  split_k<<<nwq4/256, 256, 0, stream>>>(wq, wqh, wql, nwq4);
  split_k<<<nwq4/256, 256, 0, stream>>>(wk, wkh, wkl, nwq4);
  split_k<<<nwq4/256, 256, 0, stream>>>(wv, wvh, wvl, nwq4);
  split_k<<<nwq4/256, 256, 0, stream>>>(wo, woh, wol, nwq4);

  rmsnorm_split_k<<<NTOK, 256, 0, stream>>>(q, attw, qnh, qnl);
  gemm_nt_split<<<dim3(8,32,3), 256, 0, stream>>>(qnh, qnl,
      wqh, wql, wkh, wkl, wvh, wvl, qh, kh, vh, nullptr, DM, DM);
  rope_bf16_k<<<NTOK*NH*32/256, 256, 0, stream>>>(qh, kh, fc, fs, qb, kb);
  vtrans_k<<<dim3(SQ/64, NB*NH), 256, 0, stream>>>(vh, vTb);
  flash_mfma_k<<<dim3(SQ/64, NB*NH), 256, 0, stream>>>(qb, kb, vTb, ctxh, ctxl, caus);
  gemm_nt_split<<<dim3(8,32,1), 256, 0, stream>>>(ctxh, ctxl,
      woh, wol, woh, wol, woh, wol, hbuf, hbuf, hbuf, q, DM, DM);
  rmsnorm_k<<<NTOK, 256, 0, stream>>>(hbuf, ffnw, hn);

  hipMemsetAsync(counts, 0, 64, stream);
  router_k<<<NTOK, 256, 0, stream>>>(hn, rw, rb, topi, topp, counts);
  offsets_k<<<1, 64, 0, stream>>>(counts, offs);
  assign_k<<<NTOK*2/256, 256, 0, stream>>>(topi, offs, cursor, list, inv);
  gather_k<<<RTOT, 256, 0, stream>>>(hn, offs, counts, list, xg);

  gemm_moe_bf16<<<dim3(FFd/128, RTOT/128), 256, 0, stream>>>(xg, w1b, h1, offs, DM, FFd);
  gemm_moe_bf16<<<dim3(FFd/128, RTOT/128), 256, 0, stream>>>(xg, w3b, h3, offs, DM, FFd);
  silu_mul_k<<<RTOT*FFd/4/256, 256, 0, stream>>>(h1, h3);
  gemm_moe_bf16<<<dim3(DM/128, RTOT/128), 256, 0, stream>>>(h1, w2b, yb, offs, FFd, DM);
  combine_k<<<NTOK, 256, 0, stream>>>(hbuf, yb, topp, inv, out);
}

// Round 2
// 1215.667 us; speedup vs baseline: 1.1639x; 1.0025x over previous
//
#include <hip/hip_runtime.h>
#include <hip/hip_bf16.h>
#include <math.h>

#define NB 4
#define SQ 1024
#define DM 1024
#define NH 16
#define HDm 64
#define NE 8
#define FFd 4096
#define NTOK 4096
#define RTOT 10240
#define EPSF 1e-6f

typedef __attribute__((ext_vector_type(8))) short bf16x8_t;
typedef __attribute__((ext_vector_type(4))) float f32x4_t;
typedef const __attribute__((address_space(1))) void* gas_t;
typedef __attribute__((address_space(3))) void* las_t;

__device__ __forceinline__ float b2f(unsigned short u){
  return __uint_as_float(((unsigned int)u) << 16);
}
__device__ __forceinline__ unsigned short f2b(float f){
  __hip_bfloat16 h = __float2bfloat16(f);
  unsigned short u;
  __builtin_memcpy(&u, &h, 2);
  return u;
}

// ---------------- fp32 -> bf16 convert ----------------
__global__ __launch_bounds__(256) void convert_k(const float* __restrict__ s,
                                                 unsigned short* __restrict__ d, int n4){
  int i = blockIdx.x*256 + threadIdx.x;
  if (i >= n4) return;
  float4 v = ((const float4*)s)[i];
  ushort4 o; o.x=f2b(v.x); o.y=f2b(v.y); o.z=f2b(v.z); o.w=f2b(v.w);
  ((ushort4*)d)[i] = o;
}

// ---------------- fp32 -> bf16 hi/lo split ----------------
__global__ __launch_bounds__(256) void split_k(const float* __restrict__ s,
                                               unsigned short* __restrict__ hi,
                                               unsigned short* __restrict__ lo, int n4){
  int i = blockIdx.x*256 + threadIdx.x;
  if (i >= n4) return;
  float4 v = ((const float4*)s)[i];
  ushort4 h, l;
  h.x=f2b(v.x); l.x=f2b(v.x - b2f(h.x));
  h.y=f2b(v.y); l.y=f2b(v.y - b2f(h.y));
  h.z=f2b(v.z); l.z=f2b(v.z - b2f(h.z));
  h.w=f2b(v.w); l.w=f2b(v.w - b2f(h.w));
  ((ushort4*)hi)[i] = h;
  ((ushort4*)lo)[i] = l;
}

// ---------------- RMSNorm (fp32 out), one block per row ----------------
__global__ __launch_bounds__(256) void rmsnorm_k(const float* __restrict__ x,
                                                 const float* __restrict__ w,
                                                 float* __restrict__ o){
  int row = blockIdx.x; int t = threadIdx.x;
  float4 v = ((const float4*)(x + (size_t)row*DM))[t];
  float ss = v.x*v.x + v.y*v.y + v.z*v.z + v.w*v.w;
  #pragma unroll
  for (int d=32; d; d>>=1) ss += __shfl_down(ss, d, 64);
  __shared__ float red[4];
  int wid = t>>6, ln = t&63;
  if (ln==0) red[wid] = ss;
  __syncthreads();
  float tot = red[0]+red[1]+red[2]+red[3];
  float sc = 1.0f/sqrtf(tot*(1.0f/DM) + EPSF);
  float4 wv = ((const float4*)w)[t];
  float4 ov = { v.x*sc*wv.x, v.y*sc*wv.y, v.z*sc*wv.z, v.w*sc*wv.w };
  ((float4*)(o + (size_t)row*DM))[t] = ov;
}

// ---------------- RMSNorm with split bf16 output ----------------
__global__ __launch_bounds__(256) void rmsnorm_split_k(const float* __restrict__ x,
                                                       const float* __restrict__ w,
                                                       unsigned short* __restrict__ hi,
                                                       unsigned short* __restrict__ lo){
  int row = blockIdx.x; int t = threadIdx.x;
  float4 v = ((const float4*)(x + (size_t)row*DM))[t];
  float ss = v.x*v.x + v.y*v.y + v.z*v.z + v.w*v.w;
  #pragma unroll
  for (int d=32; d; d>>=1) ss += __shfl_down(ss, d, 64);
  __shared__ float red[4];
  int wid = t>>6, ln = t&63;
  if (ln==0) red[wid] = ss;
  __syncthreads();
  float tot = red[0]+red[1]+red[2]+red[3];
  float sc = 1.0f/sqrtf(tot*(1.0f/DM) + EPSF);
  float4 wv = ((const float4*)w)[t];
  float4 ov = { v.x*sc*wv.x, v.y*sc*wv.y, v.z*sc*wv.z, v.w*sc*wv.w };
  ushort4 h, l;
  h.x=f2b(ov.x); l.x=f2b(ov.x - b2f(h.x));
  h.y=f2b(ov.y); l.y=f2b(ov.y - b2f(h.y));
  h.z=f2b(ov.z); l.z=f2b(ov.z - b2f(h.z));
  h.w=f2b(ov.w); l.w=f2b(ov.w - b2f(h.w));
  ((ushort4*)(hi + (size_t)row*DM))[t] = h;
  ((ushort4*)(lo + (size_t)row*DM))[t] = l;
}

// ---------------- split-bf16 MFMA NT GEMM: C = (Ah+Al)@(Bh+Bl)^T (+resid) ------
__global__ __launch_bounds__(256) void gemm_nt_split(
  const unsigned short* __restrict__ Ah, const unsigned short* __restrict__ Al,
  const unsigned short* __restrict__ Bh0, const unsigned short* __restrict__ Bl0,
  const unsigned short* __restrict__ Bh1, const unsigned short* __restrict__ Bl1,
  const unsigned short* __restrict__ Bh2, const unsigned short* __restrict__ Bl2,
  float* __restrict__ C0, float* __restrict__ C1, float* __restrict__ C2,
  const float* __restrict__ resid, int Kd, int Ncols)
{
  const unsigned short* Bh = (blockIdx.z==0)?Bh0:(blockIdx.z==1)?Bh1:Bh2;
  const unsigned short* Bl = (blockIdx.z==0)?Bl0:(blockIdx.z==1)?Bl1:Bl2;
  float* C = (blockIdx.z==0)?C0:(blockIdx.z==1)?C1:C2;
  __shared__ unsigned short AsH[128*32];
  __shared__ unsigned short AsL[128*32];
  __shared__ unsigned short BsH[128*32];
  __shared__ unsigned short BsL[128*32];
  const int t = threadIdx.x;
  const int w = t>>6, lane = t&63;
  const int wm = w>>1, wn = w&1;
  const int lm = lane&15, fk = (lane>>4)*8;
  const int row0 = blockIdx.y*128, col0 = blockIdx.x*128;
  f32x4_t acc[4][4];
  #pragma unroll
  for (int i=0;i<4;i++)
    #pragma unroll
    for (int j=0;j<4;j++){ f32x4_t z = {0.f,0.f,0.f,0.f}; acc[i][j]=z; }
  for (int k0=0;k0<Kd;k0+=32){
    __syncthreads();
    #pragma unroll
    for (int j=0;j<2;j++){
      const int chunk = j*4 + w;
      const int gt = chunk*64 + lane;
      const int rw_ = gt>>2, kp = (gt&3)*8;
      const size_t aoff = (size_t)(row0+rw_)*Kd + k0 + kp;
      const size_t boff = (size_t)(col0+rw_)*Kd + k0 + kp;
      __builtin_amdgcn_global_load_lds((gas_t)(Ah + aoff), (las_t)(AsH + chunk*512), 16, 0, 0);
      __builtin_amdgcn_global_load_lds((gas_t)(Al + aoff), (las_t)(AsL + chunk*512), 16, 0, 0);
      __builtin_amdgcn_global_load_lds((gas_t)(Bh + boff), (las_t)(BsH + chunk*512), 16, 0, 0);
      __builtin_amdgcn_global_load_lds((gas_t)(Bl + boff), (las_t)(BsL + chunk*512), 16, 0, 0);
    }
    __syncthreads();
    bf16x8_t ah[4], al[4], bh[4], bl[4];
    #pragma unroll
    for (int f=0;f<4;f++){
      const size_t ao = (size_t)(wm*64 + f*16 + lm)*32 + fk;
      const size_t bo = (size_t)(wn*64 + f*16 + lm)*32 + fk;
      ah[f] = *(const bf16x8_t*)(AsH + ao);
      al[f] = *(const bf16x8_t*)(AsL + ao);
      bh[f] = *(const bf16x8_t*)(BsH + bo);
      bl[f] = *(const bf16x8_t*)(BsL + bo);
    }
    #pragma unroll
    for (int i=0;i<4;i++)
      #pragma unroll
      for (int j=0;j<4;j++){
        acc[i][j] = __builtin_amdgcn_mfma_f32_16x16x32_bf16(ah[i], bh[j], acc[i][j], 0, 0, 0);
        acc[i][j] = __builtin_amdgcn_mfma_f32_16x16x32_bf16(al[i], bh[j], acc[i][j], 0, 0, 0);
        acc[i][j] = __builtin_amdgcn_mfma_f32_16x16x32_bf16(ah[i], bl[j], acc[i][j], 0, 0, 0);
      }
  }
  const int rbase = row0 + wm*64 + (lane>>4)*4;
  const int cbase = col0 + wn*64 + lm;
  #pragma unroll
  for (int i=0;i<4;i++)
    #pragma unroll
    for (int j=0;j<4;j++)
      #pragma unroll
      for (int r=0;r<4;r++){
        const size_t idx = (size_t)(rbase + i*16 + r)*Ncols + cbase + j*16;
        float v = acc[i][j][r];
        if (resid) v += resid[idx];
        C[idx] = v;
      }
}

// ---------------- RoPE -> bf16 (q scaled by 1/8 for attention) ----------------
__global__ __launch_bounds__(256) void rope_bf16_k(const float* __restrict__ qh,
  const float* __restrict__ kh, const float* __restrict__ fc, const float* __restrict__ fs,
  unsigned short* __restrict__ qb, unsigned short* __restrict__ kb){
  int idx = blockIdx.x*256 + threadIdx.x;
  if (idx >= NTOK*NH*32) return;
  int i = idx & 31;
  int h = (idx>>5) & (NH-1);
  int n = idx >> 9;
  int s = n & (SQ-1);
  float c = fc[s*32+i], sn = fs[s*32+i];
  size_t base = (size_t)n*DM + h*HDm + 2*i;
  float xr = qh[base], xi = qh[base+1];
  float or_ = (xr*c - xi*sn) * 0.125f;
  float oi  = (xr*sn + xi*c) * 0.125f;
  unsigned int pq = (unsigned int)f2b(or_) | ((unsigned int)f2b(oi) << 16);
  *(unsigned int*)(qb + base) = pq;
  xr = kh[base]; xi = kh[base+1];
  or_ = xr*c - xi*sn; oi = xr*sn + xi*c;
  unsigned int pk = (unsigned int)f2b(or_) | ((unsigned int)f2b(oi) << 16);
  *(unsigned int*)(kb + base) = pk;
}

// ---------------- V transpose+convert: vh fp32 [tok][DM] -> vT bf16 [(b,h,hd)][S] ----
__global__ __launch_bounds__(256) void vtrans_k(const float* __restrict__ vh,
                                                unsigned short* __restrict__ vT){
  __shared__ unsigned short Lt[64][72];
  const int st = blockIdx.x, bh = blockIdx.y;
  const int b = bh >> 4, h = bh & 15;
  const int t = threadIdx.x;
  const int s0 = st*64;
  const int sr = t >> 2, hq = (t & 3) * 16;
  const float* src = vh + ((size_t)(b*SQ + s0 + sr))*DM + h*HDm + hq;
  #pragma unroll
  for (int i=0;i<4;i++){
    float4 v = *(const float4*)(src + 4*i);
    Lt[hq+4*i+0][sr] = f2b(v.x);
    Lt[hq+4*i+1][sr] = f2b(v.y);
    Lt[hq+4*i+2][sr] = f2b(v.z);
    Lt[hq+4*i+3][sr] = f2b(v.w);
  }
  __syncthreads();
  const int hd = t >> 2, sq = (t & 3) * 16;
  unsigned short* dst = vT + ((size_t)bh*HDm + hd)*SQ + s0 + sq;
  #pragma unroll
  for (int i=0;i<2;i++){
    bf16x8_t x = *(const bf16x8_t*)&Lt[hd][sq + 8*i];
    *(bf16x8_t*)(dst + 8*i) = x;
  }
}

// ---------------- MFMA flash attention, 64 q-rows x 64-key tiles --------------
__global__ __launch_bounds__(256) void flash_mfma_k(
  const unsigned short* __restrict__ qb, const unsigned short* __restrict__ kb,
  const unsigned short* __restrict__ vT,
  unsigned short* __restrict__ ctxh, unsigned short* __restrict__ ctxl,
  const int* __restrict__ causp)
{
  __shared__ unsigned short Qs[2*64*32];   // [c][qrow][32]
  __shared__ unsigned short Ks[2*64*32];   // [c][key][32]
  __shared__ unsigned short Vt[2*64*32];   // [c=key/32][hd][key&31]
  __shared__ unsigned short Ps[2*64*32];   // [c=key/32][qrow][key&31], XOR-swizzled
  const int qt = blockIdx.x;
  const int bh = blockIdx.y;
  const int b = bh >> 4, h = bh & 15;
  const int t = threadIdx.x;
  const int w = t >> 6, lane = t & 63;
  const int lm = lane & 15, g = lane >> 4, fk = g * 8;
  const int q0 = qt * 64;
  const size_t qkoff = (size_t)b * SQ * DM + (size_t)h * HDm;
  const size_t voff  = ((size_t)bh * HDm) * SQ;

  #pragma unroll
  for (int j=0;j<2;j++){
    const int s = j*4 + w;
    const int c = s >> 2, r0 = (s & 3) * 16;
    const int row = r0 + (lane >> 2), kp = (lane & 3) * 8;
    __builtin_amdgcn_global_load_lds((gas_t)(qb + qkoff + (size_t)(q0+row)*DM + c*32 + kp),
                                     (las_t)(Qs + s*512), 16, 0, 0);
  }
  __syncthreads();
  bf16x8_t aq0 = *(const bf16x8_t*)(Qs + 0*2048 + (w*16+lm)*32 + fk);
  bf16x8_t aq1 = *(const bf16x8_t*)(Qs + 1*2048 + (w*16+lm)*32 + fk);

  const int causal = *causp;
  const int ktmax = causal ? qt : (SQ/64 - 1);
  f32x4_t O[4];
  #pragma unroll
  for (int j=0;j<4;j++){ f32x4_t z={0.f,0.f,0.f,0.f}; O[j]=z; }
  float mrow[4], lrow[4];
  #pragma unroll
  for (int r=0;r<4;r++){ mrow[r] = -3e30f; lrow[r] = 0.f; }

  for (int kt=0; kt<=ktmax; ++kt){
    const int k0 = kt*64;
    __syncthreads();
    #pragma unroll
    for (int j=0;j<2;j++){
      const int s = j*4 + w;
      const int c = s >> 2, r0 = (s & 3) * 16;
      const int row = r0 + (lane >> 2), kp = (lane & 3) * 8;
      __builtin_amdgcn_global_load_lds((gas_t)(kb + qkoff + (size_t)(k0+row)*DM + c*32 + kp),
                                       (las_t)(Ks + s*512), 16, 0, 0);
      __builtin_amdgcn_global_load_lds((gas_t)(vT + voff + (size_t)row*SQ + k0 + c*32 + kp),
                                       (las_t)(Vt + s*512), 16, 0, 0);
    }
    __syncthreads();

    f32x4_t Sv[4];
    #pragma unroll
    for (int j=0;j<4;j++){ f32x4_t z={0.f,0.f,0.f,0.f}; Sv[j]=z; }
    #pragma unroll
    for (int j=0;j<4;j++){
      bf16x8_t b0 = *(const bf16x8_t*)(Ks + 0*2048 + (j*16+lm)*32 + fk);
      bf16x8_t b1 = *(const bf16x8_t*)(Ks + 1*2048 + (j*16+lm)*32 + fk);
      Sv[j] = __builtin_amdgcn_mfma_f32_16x16x32_bf16(aq0, b0, Sv[j], 0, 0, 0);
      Sv[j] = __builtin_amdgcn_mfma_f32_16x16x32_bf16(aq1, b1, Sv[j], 0, 0, 0);
    }
    const int rowq = q0 + w*16 + g*4;
    if (causal && kt == qt){
      #pragma unroll
      for (int j=0;j<4;j++){
        const int col = k0 + j*16 + lm;
        #pragma unroll
        for (int r=0;r<4;r++)
          if (col > rowq + r) Sv[j][r] = -3e30f;
      }
    }
    float alpha[4];
    #pragma unroll
    for (int r=0;r<4;r++){
      float m_ = fmaxf(fmaxf(Sv[0][r],Sv[1][r]), fmaxf(Sv[2][r],Sv[3][r]));
      #pragma unroll
      for (int d=1; d<16; d<<=1) m_ = fmaxf(m_, __shfl_xor(m_, d, 64));
      const float mn = fmaxf(mrow[r], m_);
      alpha[r] = __expf(mrow[r] - mn);
      mrow[r] = mn;
    }
    #pragma unroll
    for (int r=0;r<4;r++){
      const int qrow = w*16 + g*4 + r;
      float rs = 0.f;
      #pragma unroll
      for (int j=0;j<4;j++){
        const float p = __expf(Sv[j][r] - mrow[r]);
        rs += p;
        const int key5 = (((j&1)<<4) | lm) ^ (g<<3);
        Ps[(j>>1)*2048 + qrow*32 + key5] = f2b(p);
      }
      #pragma unroll
      for (int d=1; d<16; d<<=1) rs += __shfl_xor(rs, d, 64);
      lrow[r] = lrow[r]*alpha[r] + rs;
      #pragma unroll
      for (int j=0;j<4;j++) O[j][r] *= alpha[r];
    }
    const int fkp = fk ^ (((lm>>2)&3)<<3);
    bf16x8_t pa0 = *(const bf16x8_t*)(Ps + 0*2048 + (w*16+lm)*32 + fkp);
    bf16x8_t pa1 = *(const bf16x8_t*)(Ps + 1*2048 + (w*16+lm)*32 + fkp);
    #pragma unroll
    for (int j=0;j<4;j++){
      bf16x8_t v0 = *(const bf16x8_t*)(Vt + 0*2048 + (j*16+lm)*32 + fk);
      bf16x8_t v1 = *(const bf16x8_t*)(Vt + 1*2048 + (j*16+lm)*32 + fk);
      O[j] = __builtin_amdgcn_mfma_f32_16x16x32_bf16(pa0, v0, O[j], 0, 0, 0);
      O[j] = __builtin_amdgcn_mfma_f32_16x16x32_bf16(pa1, v1, O[j], 0, 0, 0);
    }
  }
  #pragma unroll
  for (int r=0;r<4;r++){
    const float il = 1.0f / lrow[r];
    const size_t rowtok = (size_t)(q0 + w*16 + g*4 + r);
    #pragma unroll
    for (int j=0;j<4;j++){
      const float v = O[j][r] * il;
      const unsigned short hi = f2b(v);
      const float lo = v - b2f(hi);
      const size_t idx = qkoff + rowtok*DM + j*16 + lm;
      ctxh[idx] = hi;
      ctxl[idx] = f2b(lo);
    }
  }
}

// ---------------- router: fp32 logits, top-2, counts ----------------
__global__ __launch_bounds__(256) void router_k(
  const float* __restrict__ hn, const float* __restrict__ rw, const float* __restrict__ rb,
  int* __restrict__ topi, float* __restrict__ topp, int* __restrict__ counts)
{
  const int n = blockIdx.x, t = threadIdx.x;
  float4 x = ((const float4*)(hn + (size_t)n*DM))[t];
  float p[NE];
  #pragma unroll
  for (int e=0;e<NE;e++){
    float4 wv = ((const float4*)(rw + (size_t)e*DM))[t];
    p[e] = x.x*wv.x + x.y*wv.y + x.z*wv.z + x.w*wv.w;
  }
  #pragma unroll
  for (int e=0;e<NE;e++)
    #pragma unroll
    for (int d=32; d; d>>=1) p[e] += __shfl_down(p[e], d, 64);
  __shared__ float red[4][NE];
  int wid=t>>6, ln=t&63;
  if (ln==0){
    #pragma unroll
    for (int e=0;e<NE;e++) red[wid][e]=p[e];
  }
  __syncthreads();
  if (t==0){
    float v1=-3e30f, v2=-3e30f; int i1=0, i2=0;
    for (int e=0;e<NE;e++){
      float v = red[0][e]+red[1][e]+red[2][e]+red[3][e]+rb[e];
      if (v > v1){ v2=v1;i2=i1; v1=v;i1=e; }
      else if (v > v2){ v2=v;i2=e; }
    }
    float ex = expf(v2-v1);
    float g1 = 1.0f/(1.0f+ex);
    float g2 = ex*g1;
    topi[2*n]=i1; topi[2*n+1]=i2;
    topp[2*n]=g1; topp[2*n+1]=g2;
    atomicAdd(&counts[i1],1); atomicAdd(&counts[i2],1);
  }
}

__global__ void offsets_k(const int* __restrict__ counts, int* __restrict__ offs){
  if (blockIdx.x==0 && threadIdx.x==0){
    int run=0;
    for (int e=0;e<NE;e++){ offs[e]=run; run += (counts[e]+255)&~255; }
    offs[NE]=run;
  }
}

__global__ __launch_bounds__(256) void assign_k(const int* __restrict__ topi,
  const int* __restrict__ offs, int* __restrict__ cursor,
  int* __restrict__ list, int* __restrict__ inv){
  int t = blockIdx.x*256 + threadIdx.x;
  if (t >= NTOK*2) return;
  int e = topi[t];
  int slot = atomicAdd(&cursor[e], 1);
  int pos = offs[e] + slot;
  list[pos] = t>>1;
  inv[t] = pos;
}

__global__ __launch_bounds__(256) void gather_k(const float* __restrict__ hn,
  const int* __restrict__ offs, const int* __restrict__ counts, const int* __restrict__ list,
  unsigned short* __restrict__ xg){
  const int p = blockIdx.x;
  if (p >= offs[NE]) return;
  int e=0;
  while (offs[e+1] <= p) ++e;
  const int t = threadIdx.x;
  ushort4 o;
  if (p - offs[e] < counts[e]){
    int n = list[p];
    float4 x = ((const float4*)(hn + (size_t)n*DM))[t];
    o.x=f2b(x.x); o.y=f2b(x.y); o.z=f2b(x.z); o.w=f2b(x.w);
  } else { o.x=0; o.y=0; o.z=0; o.w=0; }
  ((ushort4*)(xg + (size_t)p*DM))[t] = o;
}

// ---------------- 256x256 MoE MFMA GEMM, BK=64, 8 waves, 2-phase dbuf ----------
// LDS layout [row][64] bf16 with byte-XOR swizzle (col ^= (row&7)<<4), achieved
// via pre-swizzled GLOBAL source + linear global_load_lds dest (rule #21).
__global__ __launch_bounds__(512, 2) void gemm_moe_bf16(
  const unsigned short* __restrict__ Aall, const unsigned short* __restrict__ Wall,
  unsigned short* __restrict__ Call, const int* __restrict__ offs, int Kd, int Ncols)
{
  __shared__ unsigned short As[2*256*64];   // 64 KB
  __shared__ unsigned short Bs[2*256*64];   // 64 KB
  const int Gx = gridDim.x;
  const int nwg = Gx * gridDim.y;           // divisible by 8 for all launches
  const int orig = blockIdx.y * Gx + blockIdx.x;
  const int wg = (orig & 7) * (nwg >> 3) + (orig >> 3);   // XCD-contiguous remap
  const int ry = wg / Gx, cx = wg - ry*Gx;
  const int row0 = ry * 256;
  if (row0 >= offs[NE]) return;
  int e = 0;
  while (offs[e+1] <= row0) ++e;
  const unsigned short* Wp = Wall + (size_t)e * Ncols * Kd;
  const int col0 = cx * 256;

  const int t = threadIdx.x;
  const int w = t >> 6, lane = t & 63;
  const int wm = w >> 2, wn = w & 3;        // wave grid 2(M) x 4(N)
  const int lm = lane & 15, g = lane >> 4;
  // staging: lane -> (row lsub of 8-row chunk, 16B slot), src col pre-swizzled
  const int lsub = lane >> 3;
  const int scol = (((lane & 7) ^ lsub) << 3);   // ushorts
  // read-side swizzle key
  const int swzr = (lm & 7) << 4;                // bytes

  f32x4_t acc[8][4];
  #pragma unroll
  for (int i=0;i<8;i++)
    #pragma unroll
    for (int j=0;j<4;j++){ f32x4_t z={0.f,0.f,0.f,0.f}; acc[i][j]=z; }

  const int KT = Kd >> 6;
  auto stage = [&](int buf, int k0){
    #pragma unroll
    for (int j=0;j<4;j++){
      const int s = j*8 + w;                // chunk 0..31 (8 rows each)
      const int rl = s*8 + lsub;
      __builtin_amdgcn_global_load_lds(
        (gas_t)(Aall + (size_t)(row0+rl)*Kd + k0 + scol),
        (las_t)(As + buf*16384 + s*512), 16, 0, 0);
      __builtin_amdgcn_global_load_lds(
        (gas_t)(Wp + (size_t)(col0+rl)*Kd + k0 + scol),
        (las_t)(Bs + buf*16384 + s*512), 16, 0, 0);
    }
  };

  stage(0, 0);
  __syncthreads();
  int cur = 0;
  for (int kt=0; kt<KT; ++kt){
    if (kt+1 < KT) stage(cur^1, (kt+1)<<6);
    const unsigned short* Ab = As + cur*16384;
    const unsigned short* Bb = Bs + cur*16384;
    #pragma unroll
    for (int half=0; half<2; ++half){
      const int cb = (half<<6) | (g<<4);          // linear col byte
      const int co = (cb ^ swzr) >> 1;            // swizzled, ushorts
      bf16x8_t a[8], bfr[4];
      #pragma unroll
      for (int f=0;f<8;f++)
        a[f] = *(const bf16x8_t*)(Ab + (wm*128 + f*16 + lm)*64 + co);
      #pragma unroll
      for (int j=0;j<4;j++)
        bfr[j] = *(const bf16x8_t*)(Bb + (wn*64 + j*16 + lm)*64 + co);
      __builtin_amdgcn_s_setprio(1);
      #pragma unroll
      for (int i=0;i<8;i++)
        #pragma unroll
        for (int j=0;j<4;j++)
          acc[i][j] = __builtin_amdgcn_mfma_f32_16x16x32_bf16(a[i], bfr[j], acc[i][j], 0, 0, 0);
      __builtin_amdgcn_s_setprio(0);
    }
    __syncthreads();   // drains this wave's vmcnt (next buf ready) + all reads of cur done
    cur ^= 1;
  }

  #pragma unroll
  for (int i=0;i<8;i++){
    const int grow = row0 + wm*128 + i*16 + g*4;
    #pragma unroll
    for (int j=0;j<4;j++){
      const int gcol = col0 + wn*64 + j*16 + lm;
      #pragma unroll
      for (int r=0;r<4;r++)
        Call[(size_t)(grow + r)*Ncols + gcol] = f2b(acc[i][j][r]);
    }
  }
}

__global__ __launch_bounds__(256) void silu_mul_k(unsigned short* __restrict__ h1,
                                                  const unsigned short* __restrict__ h3){
  size_t i = (size_t)blockIdx.x*256 + threadIdx.x;
  ushort4 a = ((const ushort4*)h1)[i];
  ushort4 b = ((const ushort4*)h3)[i];
  ushort4 o;
  float fa, fb, s_;
  fa=b2f(a.x); fb=b2f(b.x); s_=fa/(1.f+__expf(-fa)); o.x=f2b(s_*fb);
  fa=b2f(a.y); fb=b2f(b.y); s_=fa/(1.f+__expf(-fa)); o.y=f2b(s_*fb);
  fa=b2f(a.z); fb=b2f(b.z); s_=fa/(1.f+__expf(-fa)); o.z=f2b(s_*fb);
  fa=b2f(a.w); fb=b2f(b.w); s_=fa/(1.f+__expf(-fa)); o.w=f2b(s_*fb);
  ((ushort4*)h1)[i] = o;
}

__global__ __launch_bounds__(256) void combine_k(const float* __restrict__ h,
  const unsigned short* __restrict__ yb, const float* __restrict__ topp,
  const int* __restrict__ inv, float* __restrict__ out)
{
  const int n = blockIdx.x, t = threadIdx.x;
  const int p0 = inv[2*n], p1 = inv[2*n+1];
  const float g0 = topp[2*n], g1 = topp[2*n+1];
  float4 hv = ((const float4*)(h + (size_t)n*DM))[t];
  ushort4 y0 = ((const ushort4*)(yb + (size_t)p0*DM))[t];
  ushort4 y1 = ((const ushort4*)(yb + (size_t)p1*DM))[t];
  float4 ov;
  ov.x = hv.x + g0*b2f(y0.x) + g1*b2f(y1.x);
  ov.y = hv.y + g0*b2f(y0.y) + g1*b2f(y1.y);
  ov.z = hv.z + g0*b2f(y0.z) + g1*b2f(y1.z);
  ov.w = hv.w + g0*b2f(y0.w) + g1*b2f(y1.w);
  ((float4*)(out + (size_t)n*DM))[t] = ov;
}

extern "C" void kernel_launch(void* const* d_in, const int* in_sizes, int n_in,
                              void* d_out, int out_size, void* d_ws, size_t ws_size,
                              hipStream_t stream)
{
  (void)in_sizes; (void)n_in; (void)out_size; (void)ws_size;
  const float* q    = (const float*)d_in[0];
  const float* fc   = (const float*)d_in[3];
  const float* fs   = (const float*)d_in[4];
  const float* attw = (const float*)d_in[5];
  const float* ffnw = (const float*)d_in[6];
  const float* wq   = (const float*)d_in[7];
  const float* wk   = (const float*)d_in[8];
  const float* wv   = (const float*)d_in[9];
  const float* wo   = (const float*)d_in[10];
  const float* rw   = (const float*)d_in[11];
  const float* rb   = (const float*)d_in[12];
  const float* w1   = (const float*)d_in[13];
  const float* w2   = (const float*)d_in[14];
  const float* w3   = (const float*)d_in[15];
  const int*   caus = (const int*)d_in[16];
  float* out = (float*)d_out;

  char* ws = (char*)d_ws;
  size_t off = 0;
  auto take = [&](size_t bytes)->char*{ char* r = ws + off; off += (bytes + 255) & ~(size_t)255; return r; };
  unsigned short* qnh = (unsigned short*)take((size_t)NTOK*DM*2);
  unsigned short* qnl = (unsigned short*)take((size_t)NTOK*DM*2);
  float* qh   = (float*)take((size_t)NTOK*DM*4);
  float* kh   = (float*)take((size_t)NTOK*DM*4);
  float* vh   = (float*)take((size_t)NTOK*DM*4);
  float* hbuf = (float*)take((size_t)NTOK*DM*4);
  unsigned short* h1  = (unsigned short*)take((size_t)RTOT*FFd*2);
  unsigned short* h3  = (unsigned short*)take((size_t)RTOT*FFd*2);
  unsigned short* yb  = (unsigned short*)take((size_t)RTOT*DM*2);
  unsigned short* w1b = (unsigned short*)take((size_t)NE*FFd*DM*2);
  unsigned short* w3b = (unsigned short*)take((size_t)NE*FFd*DM*2);
  unsigned short* w2b = (unsigned short*)take((size_t)NE*FFd*DM*2);
  int*   counts = (int*)take(64);
  int*   cursor = counts + 8;
  int*   offs   = (int*)take(64);
  int*   topi   = (int*)take((size_t)NTOK*2*4);
  float* topp   = (float*)take((size_t)NTOK*2*4);
  int*   list   = (int*)take((size_t)RTOT*4);
  int*   inv    = (int*)take((size_t)NTOK*2*4);

  // aliases (lifetimes disjoint):
  unsigned short* ctxh = qnh;                     // flash ctx hi/lo overwrite qn splits
  unsigned short* ctxl = qnl;
  float* hn = kh;                                 // rmsnorm2 output overwrites kh (dead post-rope)
  unsigned short* xg = yb;                        // gathered tokens; dead before yb written
  unsigned short* wqh = (unsigned short*)h1;      // attn weight splits live in h1 region (dead before MoE)
  unsigned short* wql = wqh + (size_t)DM*DM;
  unsigned short* wkh = wql + (size_t)DM*DM;
  unsigned short* wkl = wkh + (size_t)DM*DM;
  unsigned short* wvh = wkl + (size_t)DM*DM;
  unsigned short* wvl = wvh + (size_t)DM*DM;
  unsigned short* woh = wvl + (size_t)DM*DM;
  unsigned short* wol = woh + (size_t)DM*DM;
  unsigned short* qb  = wqh + 8*(size_t)DM*DM;    // bf16 roped Q (dead before MoE writes h1)
  unsigned short* kb  = qb + (size_t)NTOK*DM;     // bf16 roped K
  unsigned short* vTb = (unsigned short*)h3;      // bf16 V^T (dead before h3 written)

  const int nw4 = NE*FFd*DM/4;  // 8388608
  convert_k<<<nw4/256, 256, 0, stream>>>(w1, w1b, nw4);
  convert_k<<<nw4/256, 256, 0, stream>>>(w3, w3b, nw4);
  convert_k<<<nw4/256, 256, 0, stream>>>(w2, w2b, nw4);

  const int nwq4 = DM*DM/4;  // 262144
  split_k<<<nwq4/256, 256, 0, stream>>>(wq, wqh, wql, nwq4);
  split_k<<<nwq4/256, 256, 0, stream>>>(wk, wkh, wkl, nwq4);
  split_k<<<nwq4/256, 256, 0, stream>>>(wv, wvh, wvl, nwq4);
  split_k<<<nwq4/256, 256, 0, stream>>>(wo, woh, wol, nwq4);

  rmsnorm_split_k<<<NTOK, 256, 0, stream>>>(q, attw, qnh, qnl);
  gemm_nt_split<<<dim3(8,32,3), 256, 0, stream>>>(qnh, qnl,
      wqh, wql, wkh, wkl, wvh, wvl, qh, kh, vh, nullptr, DM, DM);
  rope_bf16_k<<<NTOK*NH*32/256, 256, 0, stream>>>(qh, kh, fc, fs, qb, kb);
  vtrans_k<<<dim3(SQ/64, NB*NH), 256, 0, stream>>>(vh, vTb);
  flash_mfma_k<<<dim3(SQ/64, NB*NH), 256, 0, stream>>>(qb, kb, vTb, ctxh, ctxl, caus);
  gemm_nt_split<<<dim3(8,32,1), 256, 0, stream>>>(ctxh, ctxl,
      woh, wol, woh, wol, woh, wol, hbuf, hbuf, hbuf, q, DM, DM);
  rmsnorm_k<<<NTOK, 256, 0, stream>>>(hbuf, ffnw, hn);

  hipMemsetAsync(counts, 0, 64, stream);
  router_k<<<NTOK, 256, 0, stream>>>(hn, rw, rb, topi, topp, counts);
  offsets_k<<<1, 64, 0, stream>>>(counts, offs);
  assign_k<<<NTOK*2/256, 256, 0, stream>>>(topi, offs, cursor, list, inv);
  gather_k<<<RTOT, 256, 0, stream>>>(hn, offs, counts, list, xg);

  gemm_moe_bf16<<<dim3(FFd/256, RTOT/256), 512, 0, stream>>>(xg, w1b, h1, offs, DM, FFd);
  gemm_moe_bf16<<<dim3(FFd/256, RTOT/256), 512, 0, stream>>>(xg, w3b, h3, offs, DM, FFd);
  silu_mul_k<<<RTOT*FFd/4/256, 256, 0, stream>>>(h1, h3);
  gemm_moe_bf16<<<dim3(DM/256, RTOT/256), 512, 0, stream>>>(h1, w2b, yb, offs, FFd, DM);
  combine_k<<<NTOK, 256, 0, stream>>>(hbuf, yb, topp, inv, out);
}